// Round 1
// baseline (197.088 us; speedup 1.0000x reference)
//
#include <hip/hip_runtime.h>
#include <math.h>

// Problem constants
#define NQ     16384      // HBEV*WBEV
#define EMB    256
#define NHEAD  8
#define HDIM   32
#define GW     128
#define GH     128

// GEMM tiling
#define BM 64
#define BN 64
#define BK 32
#define PAD 68            // row length in floats; 272 B -> 16B aligned rows

// ---------------------------------------------------------------------------
// Generic fp32 GEMM: C[M][256] = A[M][256] @ B[256][256] + bias (+ resid)
// Used for vproj (resid=nullptr, M=32768) and out-proj (resid=query, M=16384)
// ---------------------------------------------------------------------------
__global__ __launch_bounds__(256)
void gemm256(const float* __restrict__ A, const float* __restrict__ B,
             const float* __restrict__ bias, float* __restrict__ C,
             const float* __restrict__ resid)
{
    __shared__ float As[BK][PAD];   // transposed: As[k][m]
    __shared__ float Bs[BK][PAD];   // Bs[k][n]
    const int tid = threadIdx.x;
    const int tx = tid & 15, ty = tid >> 4;
    const int m0 = blockIdx.x * BM;
    const int n0 = blockIdx.y * BN;
    const int K = 256;

    float acc[4][4] = {};
    for (int k0 = 0; k0 < K; k0 += BK) {
        #pragma unroll
        for (int l = 0; l < 2; ++l) {
            int e = (tid + l * 256) * 4;
            int r = e >> 5;           // / BK
            int c = e & 31;
            float4 a = *reinterpret_cast<const float4*>(&A[(size_t)(m0 + r) * K + k0 + c]);
            As[c + 0][r] = a.x; As[c + 1][r] = a.y; As[c + 2][r] = a.z; As[c + 3][r] = a.w;
        }
        #pragma unroll
        for (int l = 0; l < 2; ++l) {
            int e = (tid + l * 256) * 4;
            int kr = e >> 6;          // / BN
            int nc = e & 63;
            *reinterpret_cast<float4*>(&Bs[kr][nc]) =
                *reinterpret_cast<const float4*>(&B[(size_t)(k0 + kr) * 256 + n0 + nc]);
        }
        __syncthreads();
        #pragma unroll
        for (int kk = 0; kk < BK; ++kk) {
            float4 a = *reinterpret_cast<const float4*>(&As[kk][ty * 4]);
            float4 b = *reinterpret_cast<const float4*>(&Bs[kk][tx * 4]);
            float av[4] = {a.x, a.y, a.z, a.w};
            float bv[4] = {b.x, b.y, b.z, b.w};
            #pragma unroll
            for (int i = 0; i < 4; ++i)
                #pragma unroll
                for (int j = 0; j < 4; ++j)
                    acc[i][j] = fmaf(av[i], bv[j], acc[i][j]);
        }
        __syncthreads();
    }
    #pragma unroll
    for (int i = 0; i < 4; ++i) {
        int row = m0 + ty * 4 + i;
        #pragma unroll
        for (int j = 0; j < 4; ++j) {
            int col = n0 + tx * 4 + j;
            float v = acc[i][j] + bias[col];
            if (resid) v += resid[(size_t)row * 256 + col];
            C[(size_t)row * 256 + col] = v;
        }
    }
}

// ---------------------------------------------------------------------------
// soaw GEMM: C[16384][192] = concat(value[:Nq], query) @ [W_so | W_aw] + bias
// K = 512, N = 192 (128 sampling-offset cols + 64 attention-weight cols)
// ---------------------------------------------------------------------------
__global__ __launch_bounds__(256)
void gemm_soaw(const float* __restrict__ value, const float* __restrict__ query,
               const float* __restrict__ W_so, const float* __restrict__ W_aw,
               const float* __restrict__ b_so, const float* __restrict__ b_aw,
               float* __restrict__ C)
{
    __shared__ float As[BK][PAD];
    __shared__ float Bs[BK][PAD];
    const int tid = threadIdx.x;
    const int tx = tid & 15, ty = tid >> 4;
    const int m0 = blockIdx.x * BM;
    const int n0 = blockIdx.y * BN;   // 0, 64, 128
    const int K = 512;

    float acc[4][4] = {};
    for (int k0 = 0; k0 < K; k0 += BK) {
        #pragma unroll
        for (int l = 0; l < 2; ++l) {
            int e = (tid + l * 256) * 4;
            int r = e >> 5;
            int c = e & 31;
            int gk = k0 + c;
            const float* src = (gk < 256) ? &value[(size_t)(m0 + r) * 256 + gk]
                                          : &query[(size_t)(m0 + r) * 256 + gk - 256];
            float4 a = *reinterpret_cast<const float4*>(src);
            As[c + 0][r] = a.x; As[c + 1][r] = a.y; As[c + 2][r] = a.z; As[c + 3][r] = a.w;
        }
        #pragma unroll
        for (int l = 0; l < 2; ++l) {
            int e = (tid + l * 256) * 4;
            int kr = e >> 6;
            int nc = e & 63;
            int gk = k0 + kr, gn = n0 + nc;
            float4 b = (gn < 128)
                ? *reinterpret_cast<const float4*>(&W_so[(size_t)gk * 128 + gn])
                : *reinterpret_cast<const float4*>(&W_aw[(size_t)gk * 64 + gn - 128]);
            *reinterpret_cast<float4*>(&Bs[kr][nc]) = b;
        }
        __syncthreads();
        #pragma unroll
        for (int kk = 0; kk < BK; ++kk) {
            float4 a = *reinterpret_cast<const float4*>(&As[kk][ty * 4]);
            float4 b = *reinterpret_cast<const float4*>(&Bs[kk][tx * 4]);
            float av[4] = {a.x, a.y, a.z, a.w};
            float bv[4] = {b.x, b.y, b.z, b.w};
            #pragma unroll
            for (int i = 0; i < 4; ++i)
                #pragma unroll
                for (int j = 0; j < 4; ++j)
                    acc[i][j] = fmaf(av[i], bv[j], acc[i][j]);
        }
        __syncthreads();
    }
    #pragma unroll
    for (int i = 0; i < 4; ++i) {
        int row = m0 + ty * 4 + i;
        #pragma unroll
        for (int j = 0; j < 4; ++j) {
            int col = n0 + tx * 4 + j;
            float bia = (col < 128) ? b_so[col] : b_aw[col - 128];
            C[(size_t)row * 192 + col] = acc[i][j] + bia;
        }
    }
}

// ---------------------------------------------------------------------------
// Deformable sampling: per q, softmax aw over 4 points per (head, nbq),
// bilinear-sample projected v (zero padding), accumulate, mean over nbq.
//   v:    [2][NQ][8][32] fp32
//   soaw: [NQ][192]  (128 so + 64 aw raw logits)
//   rp:   [NQ][2]
//   outm: [NQ][256]
// Block = 256 threads = one q (thread t: h = t/32, d = t%32)
// ---------------------------------------------------------------------------
__global__ __launch_bounds__(256)
void sampler(const float* __restrict__ v, const float* __restrict__ soaw,
             const float* __restrict__ rp, float* __restrict__ outm)
{
    __shared__ float so_s[128];
    __shared__ float aw_s[64];
    __shared__ float w_s[16][4];
    __shared__ float rp_s[2];

    const int q = blockIdx.x;
    const int t = threadIdx.x;
    const float* row = soaw + (size_t)q * 192;

    if (t < 128) so_s[t] = row[t];
    if (t >= 128 && t < 192) aw_s[t - 128] = row[t];
    if (t == 0) { rp_s[0] = rp[q * 2 + 0]; rp_s[1] = rp[q * 2 + 1]; }
    __syncthreads();

    if (t < 16) {   // softmax over the 4 points of pair (h = t/2, b = t%2)
        float m = aw_s[t * 4];
        #pragma unroll
        for (int p = 1; p < 4; ++p) m = fmaxf(m, aw_s[t * 4 + p]);
        float e[4], s = 0.f;
        #pragma unroll
        for (int p = 0; p < 4; ++p) { e[p] = expf(aw_s[t * 4 + p] - m); s += e[p]; }
        float inv = 1.f / s;
        #pragma unroll
        for (int p = 0; p < 4; ++p) w_s[t][p] = e[p] * inv;
    }
    __syncthreads();

    const int h = t >> 5, d = t & 31;
    const float rpx = rp_s[0], rpy = rp_s[1];
    float acc = 0.f;

    #pragma unroll
    for (int b = 0; b < 2; ++b) {
        const float* vb = v + (size_t)b * NQ * 256 + h * 32 + d;
        #pragma unroll
        for (int p = 0; p < 4; ++p) {
            float sox = so_s[h * 16 + b * 8 + p * 2 + 0];
            float soy = so_s[h * 16 + b * 8 + p * 2 + 1];
            // replicate reference arithmetic: loc = rp + so/128; px = loc*128 - 0.5
            float locx = rpx + sox * (1.0f / 128.0f);
            float locy = rpy + soy * (1.0f / 128.0f);
            float px = locx * 128.0f - 0.5f;
            float py = locy * 128.0f - 0.5f;
            float x0f = floorf(px), y0f = floorf(py);
            float lx = px - x0f, ly = py - y0f;
            int x0 = (int)x0f, y0 = (int)y0f;
            int x1 = x0 + 1, y1 = y0 + 1;
            bool xv0 = (x0 >= 0) && (x0 < GW);
            bool xv1 = (x1 >= 0) && (x1 < GW);
            bool yv0 = (y0 >= 0) && (y0 < GH);
            bool yv1 = (y1 >= 0) && (y1 < GH);
            float s00 = 0.f, s10 = 0.f, s01 = 0.f, s11 = 0.f;
            if (xv0 && yv0) s00 = vb[(size_t)(y0 * GW + x0) * 256];
            if (xv1 && yv0) s10 = vb[(size_t)(y0 * GW + x1) * 256];
            if (xv0 && yv1) s01 = vb[(size_t)(y1 * GW + x0) * 256];
            if (xv1 && yv1) s11 = vb[(size_t)(y1 * GW + x1) * 256];
            float val = (1.f - lx) * (1.f - ly) * s00 + lx * (1.f - ly) * s10
                      + (1.f - lx) * ly * s01 + lx * ly * s11;
            acc = fmaf(w_s[h * 2 + b][p], val, acc);
        }
    }
    outm[(size_t)q * 256 + t] = 0.5f * acc;
}

// ---------------------------------------------------------------------------
extern "C" void kernel_launch(void* const* d_in, const int* in_sizes, int n_in,
                              void* d_out, int out_size, void* d_ws, size_t ws_size,
                              hipStream_t stream)
{
    const float* query   = (const float*)d_in[0];
    const float* value   = (const float*)d_in[1];
    const float* rp      = (const float*)d_in[2];
    const float* W_vproj = (const float*)d_in[3];
    const float* b_vproj = (const float*)d_in[4];
    const float* W_so    = (const float*)d_in[5];
    const float* b_so    = (const float*)d_in[6];
    const float* W_aw    = (const float*)d_in[7];
    const float* b_aw    = (const float*)d_in[8];
    const float* W_out   = (const float*)d_in[9];
    const float* b_out   = (const float*)d_in[10];
    float* out = (float*)d_out;

    float* ws_v    = (float*)d_ws;                          // [2*NQ][256]  33.5 MB
    float* ws_soaw = ws_v    + (size_t)2 * NQ * 256;        // [NQ][192]    12.6 MB
    float* ws_mean = ws_soaw + (size_t)NQ * 192;            // [NQ][256]    16.8 MB

    dim3 blk(256);
    // 1. value projection: [32768,256] @ [256,256]
    gemm256<<<dim3(2 * NQ / BM, 256 / BN), blk, 0, stream>>>(value, W_vproj, b_vproj, ws_v, nullptr);
    // 2. sampling offsets + attention logits: [16384,512] @ [512,192]
    gemm_soaw<<<dim3(NQ / BM, 192 / BN), blk, 0, stream>>>(value, query, W_so, W_aw, b_so, b_aw, ws_soaw);
    // 3. softmax + bilinear deformable sampling + nbq-mean
    sampler<<<dim3(NQ), blk, 0, stream>>>(ws_v, ws_soaw, rp, ws_mean);
    // 4. output projection + residual
    gemm256<<<dim3(NQ / BM, 256 / BN), blk, 0, stream>>>(ws_mean, W_out, b_out, out, query);
}

// Round 2
// 181.561 us; speedup vs baseline: 1.0855x; 1.0855x over previous
//
#include <hip/hip_runtime.h>
#include <math.h>

#define NQ     16384
#define NHEAD  8
#define GW     128
#define GH     128

typedef __attribute__((ext_vector_type(8))) short short8;
typedef __attribute__((ext_vector_type(4))) float f32x4;

static __device__ __forceinline__ unsigned short f2bf(float f) {
    unsigned u = __builtin_bit_cast(unsigned, f);
    u += 0x7FFFu + ((u >> 16) & 1u);          // RNE
    return (unsigned short)(u >> 16);
}
static __device__ __forceinline__ unsigned pk2(float lo, float hi) {
    return (unsigned)f2bf(lo) | ((unsigned)f2bf(hi) << 16);
}
static __device__ __forceinline__ float bf2f(unsigned short h) {
    return __builtin_bit_cast(float, (unsigned)h << 16);
}

// ---------------------------------------------------------------------------
// prep: build bf16 transposed weights  WT[n][k] = W[k][n]  (+ padded soaw)
//   WTv [256][256], WTso [256][512] (n>=192 zero), WTo [256][256], bias2[256]
// ---------------------------------------------------------------------------
__global__ void prep(const float* __restrict__ Wv, const float* __restrict__ Wso,
                     const float* __restrict__ Waw, const float* __restrict__ bso,
                     const float* __restrict__ baw, const float* __restrict__ Wo,
                     unsigned short* __restrict__ WTv, unsigned short* __restrict__ WTso,
                     unsigned short* __restrict__ WTo, float* __restrict__ bias2)
{
    const int n = blockIdx.x;     // 0..255
    const int k = threadIdx.x;    // 0..255
    WTv[n * 256 + k] = f2bf(Wv[(size_t)k * 256 + n]);
    WTo[n * 256 + k] = f2bf(Wo[(size_t)k * 256 + n]);
    float s0, s1;
    if (n < 128)      { s0 = Wso[(size_t)k * 128 + n];       s1 = Wso[(size_t)(k + 256) * 128 + n]; }
    else if (n < 192) { s0 = Waw[(size_t)k * 64 + n - 128];  s1 = Waw[(size_t)(k + 256) * 64 + n - 128]; }
    else              { s0 = 0.f; s1 = 0.f; }
    WTso[(size_t)n * 512 + k]       = f2bf(s0);
    WTso[(size_t)n * 512 + k + 256] = f2bf(s1);
    if (k == 0) bias2[n] = (n < 128) ? bso[n] : ((n < 192) ? baw[n - 128] : 0.f);
}

// ---------------------------------------------------------------------------
// bf16 MFMA GEMM, tile 128x128, BK=64, 4 waves (2x2), each wave 64x64.
// LDS plane layout: As[(oct*128+row)*8 + (k&7)], oct = k>>3 (8 planes).
// MODE 0: vproj  (A=fp32 A1, out bf16 ldc256, +bias)
// MODE 1: soaw   (A=concat(A1,A2) fp32, out fp32 ldc192 col<192, +bias)
// MODE 2: outproj(A=bf16 Abf,  out fp32 ldc256, +bias +resid)
// ---------------------------------------------------------------------------
template<int KTOT, int MODE>
__global__ __launch_bounds__(256, 2)
void gemm_mfma(const float* __restrict__ A1, const float* __restrict__ A2,
               const unsigned short* __restrict__ Abf,
               const unsigned short* __restrict__ WT,
               const float* __restrict__ bias, const float* __restrict__ resid,
               void* __restrict__ Cout)
{
    __shared__ __align__(16) unsigned short As[8 * 128 * 8];   // 16 KB
    __shared__ __align__(16) unsigned short Bs[8 * 128 * 8];   // 16 KB

    const int tid = threadIdx.x;
    const int m0 = blockIdx.x * 128;
    const int n0 = blockIdx.y * 128;
    const int w = tid >> 6, lane = tid & 63;
    const int wr = w >> 1, wc = w & 1;
    const int g = lane >> 4, r16 = lane & 15;

    f32x4 acc[4][4] = {};

    for (int k0 = 0; k0 < KTOT; k0 += 64) {
        // ---- stage A (128 rows x 64 k) ----
        if (MODE == 2) {
            #pragma unroll
            for (int c = 0; c < 4; ++c) {
                int idx = tid + c * 256;
                int row = idx >> 3, oct = idx & 7;
                uint4 wv = *reinterpret_cast<const uint4*>(
                    &Abf[(size_t)(m0 + row) * 256 + k0 + oct * 8]);
                *reinterpret_cast<uint4*>(&As[(oct * 128 + row) * 8]) = wv;
            }
        } else {
            const float* Asrc = (KTOT == 512 && k0 >= 256) ? (A2 + (k0 - 256)) : (A1 + k0);
            #pragma unroll
            for (int c = 0; c < 4; ++c) {
                int idx = tid + c * 256;
                int row = idx >> 3, oct = idx & 7;
                const float* p = Asrc + (size_t)(m0 + row) * 256 + oct * 8;
                float4 f0 = *reinterpret_cast<const float4*>(p);
                float4 f1 = *reinterpret_cast<const float4*>(p + 4);
                uint4 wv;
                wv.x = pk2(f0.x, f0.y); wv.y = pk2(f0.z, f0.w);
                wv.z = pk2(f1.x, f1.y); wv.w = pk2(f1.z, f1.w);
                *reinterpret_cast<uint4*>(&As[(oct * 128 + row) * 8]) = wv;
            }
        }
        // ---- stage B (128 n x 64 k) from pre-transposed bf16 WT ----
        #pragma unroll
        for (int c = 0; c < 4; ++c) {
            int idx = tid + c * 256;
            int n = idx >> 3, oct = idx & 7;
            uint4 wv = *reinterpret_cast<const uint4*>(
                &WT[(size_t)(n0 + n) * KTOT + k0 + oct * 8]);
            *reinterpret_cast<uint4*>(&Bs[(oct * 128 + n) * 8]) = wv;
        }
        __syncthreads();

        #pragma unroll
        for (int kh = 0; kh < 2; ++kh) {
            short8 af[4], bfr[4];
            #pragma unroll
            for (int m = 0; m < 4; ++m)
                af[m] = *reinterpret_cast<const short8*>(
                    &As[(((kh * 4 + g) * 128) + wr * 64 + m * 16 + r16) * 8]);
            #pragma unroll
            for (int n = 0; n < 4; ++n)
                bfr[n] = *reinterpret_cast<const short8*>(
                    &Bs[(((kh * 4 + g) * 128) + wc * 64 + n * 16 + r16) * 8]);
            #pragma unroll
            for (int m = 0; m < 4; ++m)
                #pragma unroll
                for (int n = 0; n < 4; ++n)
                    acc[m][n] = __builtin_amdgcn_mfma_f32_16x16x32_bf16(
                        af[m], bfr[n], acc[m][n], 0, 0, 0);
        }
        __syncthreads();
    }

    // ---- epilogue: C/D layout col = lane&15, row = (lane>>4)*4 + j ----
    #pragma unroll
    for (int m = 0; m < 4; ++m) {
        int row = m0 + wr * 64 + m * 16 + g * 4;
        #pragma unroll
        for (int n = 0; n < 4; ++n) {
            int col = n0 + wc * 64 + n * 16 + r16;
            if (MODE == 1 && col >= 192) continue;
            float bia = bias[col];
            #pragma unroll
            for (int j = 0; j < 4; ++j) {
                float vo = acc[m][n][j] + bia;
                if (MODE == 0) {
                    ((unsigned short*)Cout)[(size_t)(row + j) * 256 + col] = f2bf(vo);
                } else if (MODE == 1) {
                    ((float*)Cout)[(size_t)(row + j) * 192 + col] = vo;
                } else {
                    ((float*)Cout)[(size_t)(row + j) * 256 + col] =
                        vo + resid[(size_t)(row + j) * 256 + col];
                }
            }
        }
    }
}

// ---------------------------------------------------------------------------
// Sampler: per q, softmax over 4 points per (head,b), bilinear sample bf16 v,
// mean over b. v: bf16 [2][NQ][256]; soaw: fp32 [NQ][192]; outm: bf16 [NQ][256]
// ---------------------------------------------------------------------------
__global__ __launch_bounds__(256)
void sampler(const unsigned short* __restrict__ v, const float* __restrict__ soaw,
             const float* __restrict__ rp, unsigned short* __restrict__ outm)
{
    __shared__ float so_s[128];
    __shared__ float aw_s[64];
    __shared__ float w_s[16][4];
    __shared__ float rp_s[2];

    const int q = blockIdx.x;
    const int t = threadIdx.x;
    const float* row = soaw + (size_t)q * 192;

    if (t < 128) so_s[t] = row[t];
    if (t >= 128 && t < 192) aw_s[t - 128] = row[t];
    if (t == 0) { rp_s[0] = rp[q * 2 + 0]; rp_s[1] = rp[q * 2 + 1]; }
    __syncthreads();

    if (t < 16) {
        float m = aw_s[t * 4];
        #pragma unroll
        for (int p = 1; p < 4; ++p) m = fmaxf(m, aw_s[t * 4 + p]);
        float e[4], s = 0.f;
        #pragma unroll
        for (int p = 0; p < 4; ++p) { e[p] = __expf(aw_s[t * 4 + p] - m); s += e[p]; }
        float inv = 1.f / s;
        #pragma unroll
        for (int p = 0; p < 4; ++p) w_s[t][p] = e[p] * inv;
    }
    __syncthreads();

    const int h = t >> 5, d = t & 31;
    const float rpx = rp_s[0], rpy = rp_s[1];
    float acc = 0.f;

    #pragma unroll
    for (int b = 0; b < 2; ++b) {
        const unsigned short* vb = v + (size_t)b * NQ * 256 + h * 32 + d;
        #pragma unroll
        for (int p = 0; p < 4; ++p) {
            float sox = so_s[h * 16 + b * 8 + p * 2 + 0];
            float soy = so_s[h * 16 + b * 8 + p * 2 + 1];
            float px = (rpx + sox * (1.0f / 128.0f)) * 128.0f - 0.5f;
            float py = (rpy + soy * (1.0f / 128.0f)) * 128.0f - 0.5f;
            float x0f = floorf(px), y0f = floorf(py);
            float lx = px - x0f, ly = py - y0f;
            int x0 = (int)x0f, y0 = (int)y0f;
            int x1 = x0 + 1, y1 = y0 + 1;
            bool xv0 = (x0 >= 0) && (x0 < GW);
            bool xv1 = (x1 >= 0) && (x1 < GW);
            bool yv0 = (y0 >= 0) && (y0 < GH);
            bool yv1 = (y1 >= 0) && (y1 < GH);
            float s00 = 0.f, s10 = 0.f, s01 = 0.f, s11 = 0.f;
            if (xv0 && yv0) s00 = bf2f(vb[(size_t)(y0 * GW + x0) * 256]);
            if (xv1 && yv0) s10 = bf2f(vb[(size_t)(y0 * GW + x1) * 256]);
            if (xv0 && yv1) s01 = bf2f(vb[(size_t)(y1 * GW + x0) * 256]);
            if (xv1 && yv1) s11 = bf2f(vb[(size_t)(y1 * GW + x1) * 256]);
            float val = (1.f - lx) * (1.f - ly) * s00 + lx * (1.f - ly) * s10
                      + (1.f - lx) * ly * s01 + lx * ly * s11;
            acc = fmaf(w_s[h * 2 + b][p], val, acc);
        }
    }
    outm[(size_t)q * 256 + t] = f2bf(0.5f * acc);
}

// ---------------------------------------------------------------------------
extern "C" void kernel_launch(void* const* d_in, const int* in_sizes, int n_in,
                              void* d_out, int out_size, void* d_ws, size_t ws_size,
                              hipStream_t stream)
{
    const float* query   = (const float*)d_in[0];
    const float* value   = (const float*)d_in[1];
    const float* rp      = (const float*)d_in[2];
    const float* W_vproj = (const float*)d_in[3];
    const float* b_vproj = (const float*)d_in[4];
    const float* W_so    = (const float*)d_in[5];
    const float* b_so    = (const float*)d_in[6];
    const float* W_aw    = (const float*)d_in[7];
    const float* b_aw    = (const float*)d_in[8];
    const float* W_out   = (const float*)d_in[9];
    const float* b_out   = (const float*)d_in[10];
    float* out = (float*)d_out;

    char* wp = (char*)d_ws;
    unsigned short* ws_v    = (unsigned short*)wp; wp += (size_t)2 * NQ * 256 * 2;
    float*          ws_soaw = (float*)wp;          wp += (size_t)NQ * 192 * 4;
    unsigned short* ws_mean = (unsigned short*)wp; wp += (size_t)NQ * 256 * 2;
    unsigned short* WTv     = (unsigned short*)wp; wp += 256 * 256 * 2;
    unsigned short* WTso    = (unsigned short*)wp; wp += 256 * 512 * 2;
    unsigned short* WTo     = (unsigned short*)wp; wp += 256 * 256 * 2;
    float*          bias2   = (float*)wp;          wp += 256 * 4;

    prep<<<dim3(256), dim3(256), 0, stream>>>(W_vproj, W_so, W_aw, b_so, b_aw, W_out,
                                              WTv, WTso, WTo, bias2);
    // vproj: [32768,256] @ [256,256] -> bf16 v
    gemm_mfma<256, 0><<<dim3(256, 2), dim3(256), 0, stream>>>(
        value, nullptr, nullptr, WTv, b_vproj, nullptr, ws_v);
    // soaw: concat(value[:NQ], query) [16384,512] @ [512,192] -> fp32
    gemm_mfma<512, 1><<<dim3(128, 2), dim3(256), 0, stream>>>(
        value, query, nullptr, WTso, bias2, nullptr, ws_soaw);
    // deformable sampling + softmax + nbq-mean -> bf16
    sampler<<<dim3(NQ), dim3(256), 0, stream>>>(ws_v, ws_soaw, rp, ws_mean);
    // outproj: [16384,256] @ [256,256] + bias + residual -> fp32
    gemm_mfma<256, 2><<<dim3(128, 2), dim3(256), 0, stream>>>(
        nullptr, nullptr, ws_mean, WTo, b_out, query, out);
}

// Round 3
// 84.436 us; speedup vs baseline: 2.3342x; 2.1503x over previous
//
#include <hip/hip_runtime.h>
#include <math.h>

#define NQ     16384
#define NHEAD  8
#define GW     128
#define GH     128

typedef __attribute__((ext_vector_type(8))) short short8;
typedef __attribute__((ext_vector_type(4))) float f32x4;

static __device__ __forceinline__ unsigned short f2bf(float f) {
    unsigned u = __builtin_bit_cast(unsigned, f);
    u += 0x7FFFu + ((u >> 16) & 1u);          // RNE
    return (unsigned short)(u >> 16);
}
static __device__ __forceinline__ unsigned pk2(float lo, float hi) {
    return (unsigned)f2bf(lo) | ((unsigned)f2bf(hi) << 16);
}

// ---------------------------------------------------------------------------
// prep: bf16 transposed weights  WT[n][k] = W[k][n]  (+ padded soaw weights)
// ---------------------------------------------------------------------------
__global__ void prep(const float* __restrict__ Wv, const float* __restrict__ Wso,
                     const float* __restrict__ Waw, const float* __restrict__ bso,
                     const float* __restrict__ baw, const float* __restrict__ Wo,
                     unsigned short* __restrict__ WTv, unsigned short* __restrict__ WTso,
                     unsigned short* __restrict__ WTo, float* __restrict__ bias2)
{
    const int n = blockIdx.x;     // 0..255
    const int k = threadIdx.x;    // 0..255
    WTv[n * 256 + k] = f2bf(Wv[(size_t)k * 256 + n]);
    WTo[n * 256 + k] = f2bf(Wo[(size_t)k * 256 + n]);
    float s0, s1;
    if (n < 128)      { s0 = Wso[(size_t)k * 128 + n];       s1 = Wso[(size_t)(k + 256) * 128 + n]; }
    else if (n < 192) { s0 = Waw[(size_t)k * 64 + n - 128];  s1 = Waw[(size_t)(k + 256) * 64 + n - 128]; }
    else              { s0 = 0.f; s1 = 0.f; }
    WTso[(size_t)n * 512 + k]       = f2bf(s0);
    WTso[(size_t)n * 512 + k + 256] = f2bf(s1);
    if (k == 0) bias2[n] = (n < 128) ? bso[n] : ((n < 192) ? baw[n - 128] : 0.f);
}

// ---------------------------------------------------------------------------
// bf16 MFMA GEMM, tile 128x128, BK=64, 4 waves (2x2), each wave 64x64.
// MODE 0: vproj  (A=fp32 A1, out bf16 ldc256, +bias)
// MODE 1: soaw   (A=concat(A1,A2) fp32, out fp32 ldc192 col<192, +bias)
// MODE 2: outproj(A=bf16 Abf,  out fp32 ldc256, +bias +resid)
// ---------------------------------------------------------------------------
template<int KTOT, int MODE>
__global__ __launch_bounds__(256, 2)
void gemm_mfma(const float* __restrict__ A1, const float* __restrict__ A2,
               const unsigned short* __restrict__ Abf,
               const unsigned short* __restrict__ WT,
               const float* __restrict__ bias, const float* __restrict__ resid,
               void* __restrict__ Cout)
{
    __shared__ __align__(16) unsigned short As[8 * 128 * 8];   // 16 KB
    __shared__ __align__(16) unsigned short Bs[8 * 128 * 8];   // 16 KB

    const int tid = threadIdx.x;
    const int m0 = blockIdx.x * 128;
    const int n0 = blockIdx.y * 128;
    const int w = tid >> 6, lane = tid & 63;
    const int wr = w >> 1, wc = w & 1;
    const int g = lane >> 4, r16 = lane & 15;

    f32x4 acc[4][4] = {};

    for (int k0 = 0; k0 < KTOT; k0 += 64) {
        if (MODE == 2) {
            #pragma unroll
            for (int c = 0; c < 4; ++c) {
                int idx = tid + c * 256;
                int row = idx >> 3, oct = idx & 7;
                uint4 wv = *reinterpret_cast<const uint4*>(
                    &Abf[(size_t)(m0 + row) * 256 + k0 + oct * 8]);
                *reinterpret_cast<uint4*>(&As[(oct * 128 + row) * 8]) = wv;
            }
        } else {
            const float* Asrc = (KTOT == 512 && k0 >= 256) ? (A2 + (k0 - 256)) : (A1 + k0);
            #pragma unroll
            for (int c = 0; c < 4; ++c) {
                int idx = tid + c * 256;
                int row = idx >> 3, oct = idx & 7;
                const float* p = Asrc + (size_t)(m0 + row) * 256 + oct * 8;
                float4 f0 = *reinterpret_cast<const float4*>(p);
                float4 f1 = *reinterpret_cast<const float4*>(p + 4);
                uint4 wv;
                wv.x = pk2(f0.x, f0.y); wv.y = pk2(f0.z, f0.w);
                wv.z = pk2(f1.x, f1.y); wv.w = pk2(f1.z, f1.w);
                *reinterpret_cast<uint4*>(&As[(oct * 128 + row) * 8]) = wv;
            }
        }
        #pragma unroll
        for (int c = 0; c < 4; ++c) {
            int idx = tid + c * 256;
            int n = idx >> 3, oct = idx & 7;
            uint4 wv = *reinterpret_cast<const uint4*>(
                &WT[(size_t)(n0 + n) * KTOT + k0 + oct * 8]);
            *reinterpret_cast<uint4*>(&Bs[(oct * 128 + n) * 8]) = wv;
        }
        __syncthreads();

        #pragma unroll
        for (int kh = 0; kh < 2; ++kh) {
            short8 af[4], bfr[4];
            #pragma unroll
            for (int m = 0; m < 4; ++m)
                af[m] = *reinterpret_cast<const short8*>(
                    &As[(((kh * 4 + g) * 128) + wr * 64 + m * 16 + r16) * 8]);
            #pragma unroll
            for (int n = 0; n < 4; ++n)
                bfr[n] = *reinterpret_cast<const short8*>(
                    &Bs[(((kh * 4 + g) * 128) + wc * 64 + n * 16 + r16) * 8]);
            #pragma unroll
            for (int m = 0; m < 4; ++m)
                #pragma unroll
                for (int n = 0; n < 4; ++n)
                    acc[m][n] = __builtin_amdgcn_mfma_f32_16x16x32_bf16(
                        af[m], bfr[n], acc[m][n], 0, 0, 0);
        }
        __syncthreads();
    }

    #pragma unroll
    for (int m = 0; m < 4; ++m) {
        int row = m0 + wr * 64 + m * 16 + g * 4;
        #pragma unroll
        for (int n = 0; n < 4; ++n) {
            int col = n0 + wc * 64 + n * 16 + r16;
            if (MODE == 1 && col >= 192) continue;
            float bia = bias[col];
            #pragma unroll
            for (int j = 0; j < 4; ++j) {
                float vo = acc[m][n][j] + bia;
                if (MODE == 0) {
                    ((unsigned short*)Cout)[(size_t)(row + j) * 256 + col] = f2bf(vo);
                } else if (MODE == 1) {
                    ((float*)Cout)[(size_t)(row + j) * 192 + col] = vo;
                } else {
                    ((float*)Cout)[(size_t)(row + j) * 256 + col] =
                        vo + resid[(size_t)(row + j) * 256 + col];
                }
            }
        }
    }
}

// ---------------------------------------------------------------------------
// Sampler v2: one WAVE per q. lane = h*8 + c  (h = head, c = 4-elem d-chunk).
// Branch-free clamped loads with multiplicative validity masks.
// v: bf16 [2][NQ][8][32]; soaw: fp32 [NQ][192]; outm: bf16 [NQ][256]
// ---------------------------------------------------------------------------
static __device__ __forceinline__ void acc4(f32x4& acc, float w, uint2 r) {
    acc[0] = fmaf(w, __builtin_bit_cast(float, r.x << 16), acc[0]);
    acc[1] = fmaf(w, __builtin_bit_cast(float, r.x & 0xffff0000u), acc[1]);
    acc[2] = fmaf(w, __builtin_bit_cast(float, r.y << 16), acc[2]);
    acc[3] = fmaf(w, __builtin_bit_cast(float, r.y & 0xffff0000u), acc[3]);
}

__global__ __launch_bounds__(256)
void sampler(const unsigned short* __restrict__ v, const float* __restrict__ soaw,
             const float* __restrict__ rp, unsigned short* __restrict__ outm)
{
    __shared__ float so_s[4][128];
    __shared__ float w_s[4][64];

    const int t = threadIdx.x;
    const int wv = t >> 6, ln = t & 63;
    const int q = blockIdx.x * 4 + wv;
    const float* row = soaw + (size_t)q * 192;

    // stage sampling offsets (128 floats / wave)
    so_s[wv][ln]      = row[ln];
    so_s[wv][64 + ln] = row[64 + ln];
    // wave-parallel softmax: lane ln holds logit (h=ln>>3, b=(ln>>2)&1, p=ln&3)
    float a = row[128 + ln];
    float m = fmaxf(a, __shfl_xor(a, 1, 4));
    m = fmaxf(m, __shfl_xor(m, 2, 4));
    float e = __expf(a - m);
    float s = e + __shfl_xor(e, 1, 4);
    s += __shfl_xor(s, 2, 4);
    w_s[wv][ln] = e / s;
    __syncthreads();

    const float rpx = rp[q * 2 + 0], rpy = rp[q * 2 + 1];
    const int h = ln >> 3, c = ln & 7;
    const int sub = h * 64 + c * 8;          // byte offset inside a 512B row
    f32x4 acc = {0.f, 0.f, 0.f, 0.f};

    #pragma unroll
    for (int b = 0; b < 2; ++b) {
        const char* vb = (const char*)v + (size_t)b * NQ * 512;
        #pragma unroll
        for (int p = 0; p < 4; ++p) {
            float sox = so_s[wv][h * 16 + b * 8 + p * 2 + 0];
            float soy = so_s[wv][h * 16 + b * 8 + p * 2 + 1];
            float wbp = w_s[wv][h * 8 + b * 4 + p];
            float px = (rpx + sox * (1.0f / 128.0f)) * 128.0f - 0.5f;
            float py = (rpy + soy * (1.0f / 128.0f)) * 128.0f - 0.5f;
            float x0f = floorf(px), y0f = floorf(py);
            float lx = px - x0f, ly = py - y0f;
            int x0 = (int)x0f, y0 = (int)y0f;
            int x1 = x0 + 1, y1 = y0 + 1;
            float wx0 = (1.f - lx) * ((x0 >= 0 && x0 < GW) ? 1.f : 0.f);
            float wx1 = lx         * ((x1 >= 0 && x1 < GW) ? 1.f : 0.f);
            float wy0 = (1.f - ly) * ((y0 >= 0 && y0 < GH) ? 1.f : 0.f);
            float wy1 = ly         * ((y1 >= 0 && y1 < GH) ? 1.f : 0.f);
            int x0c = min(max(x0, 0), GW - 1), x1c = min(max(x1, 0), GW - 1);
            int y0c = min(max(y0, 0), GH - 1), y1c = min(max(y1, 0), GH - 1);
            uint2 r00 = *(const uint2*)(vb + ((y0c * GW + x0c) * 512 + sub));
            uint2 r10 = *(const uint2*)(vb + ((y0c * GW + x1c) * 512 + sub));
            uint2 r01 = *(const uint2*)(vb + ((y1c * GW + x0c) * 512 + sub));
            uint2 r11 = *(const uint2*)(vb + ((y1c * GW + x1c) * 512 + sub));
            acc4(acc, wbp * wx0 * wy0, r00);
            acc4(acc, wbp * wx1 * wy0, r10);
            acc4(acc, wbp * wx0 * wy1, r01);
            acc4(acc, wbp * wx1 * wy1, r11);
        }
    }

    uint2 o;
    o.x = pk2(0.5f * acc[0], 0.5f * acc[1]);
    o.y = pk2(0.5f * acc[2], 0.5f * acc[3]);
    *reinterpret_cast<uint2*>(&outm[(size_t)q * 256 + h * 32 + c * 4]) = o;
}

// ---------------------------------------------------------------------------
extern "C" void kernel_launch(void* const* d_in, const int* in_sizes, int n_in,
                              void* d_out, int out_size, void* d_ws, size_t ws_size,
                              hipStream_t stream)
{
    const float* query   = (const float*)d_in[0];
    const float* value   = (const float*)d_in[1];
    const float* rp      = (const float*)d_in[2];
    const float* W_vproj = (const float*)d_in[3];
    const float* b_vproj = (const float*)d_in[4];
    const float* W_so    = (const float*)d_in[5];
    const float* b_so    = (const float*)d_in[6];
    const float* W_aw    = (const float*)d_in[7];
    const float* b_aw    = (const float*)d_in[8];
    const float* W_out   = (const float*)d_in[9];
    const float* b_out   = (const float*)d_in[10];
    float* out = (float*)d_out;

    char* wp = (char*)d_ws;
    unsigned short* ws_v    = (unsigned short*)wp; wp += (size_t)2 * NQ * 256 * 2;
    float*          ws_soaw = (float*)wp;          wp += (size_t)NQ * 192 * 4;
    unsigned short* ws_mean = (unsigned short*)wp; wp += (size_t)NQ * 256 * 2;
    unsigned short* WTv     = (unsigned short*)wp; wp += 256 * 256 * 2;
    unsigned short* WTso    = (unsigned short*)wp; wp += 256 * 512 * 2;
    unsigned short* WTo     = (unsigned short*)wp; wp += 256 * 256 * 2;
    float*          bias2   = (float*)wp;          wp += 256 * 4;

    prep<<<dim3(256), dim3(256), 0, stream>>>(W_vproj, W_so, W_aw, b_so, b_aw, W_out,
                                              WTv, WTso, WTo, bias2);
    gemm_mfma<256, 0><<<dim3(256, 2), dim3(256), 0, stream>>>(
        value, nullptr, nullptr, WTv, b_vproj, nullptr, ws_v);
    gemm_mfma<512, 1><<<dim3(128, 2), dim3(256), 0, stream>>>(
        value, query, nullptr, WTso, bias2, nullptr, ws_soaw);
    sampler<<<dim3(NQ / 4), dim3(256), 0, stream>>>(ws_v, ws_soaw, rp, ws_mean);
    gemm_mfma<256, 2><<<dim3(128, 2), dim3(256), 0, stream>>>(
        nullptr, nullptr, ws_mean, WTo, b_out, query, out);
}